// Round 1
// baseline (1553.546 us; speedup 1.0000x reference)
//
#include <hip/hip_runtime.h>
#include <stdint.h>

// Problem constants (fixed by the reference file)
#define Bsz 1024
#define Lsz 4096
#define Dsz 64
#define Ksz 64

// ---------------------------------------------------------------------------
// Mask-format detection: seq_mask is bool in the reference. The harness may
// hand it to us as 1-byte bool or as int32. Values are only 0/1, so:
//   - int32 layout: every byte at offset %4 != 0 is zero.
//   - uint8  layout: ~50% of those bytes are 1 (random mask).
// Scan the first 64 KB; certain discrimination. Flag=1 -> uint8, 0 -> int32.
// ---------------------------------------------------------------------------
__global__ void detect_mask_fmt(const uint8_t* __restrict__ m, int* __restrict__ flag) {
    __shared__ int s_any;
    if (threadIdx.x == 0) s_any = 0;
    __syncthreads();
    int any = 0;
    for (int i = threadIdx.x; i < 65536; i += blockDim.x) {
        if ((i & 3) != 0 && m[i] != 0) any = 1;
    }
    if (any) s_any = 1;  // benign race
    __syncthreads();
    if (threadIdx.x == 0) *flag = s_any;
}

// ---------------------------------------------------------------------------
// One block (256 threads = 4 waves) per batch row b.
// ---------------------------------------------------------------------------
__global__ __launch_bounds__(256) void gsu_kernel(
    const float* __restrict__ target,   // [B, D]
    const float* __restrict__ seq,      // [B, L, D]
    const void*  __restrict__ maskp,    // [B, L] bool (uint8 or int32)
    const float* __restrict__ W,        // [D, D]
    const int*   __restrict__ flag,
    float*       __restrict__ out)      // [B*K*D] emb, then [B*K] mask (0/1)
{
    __shared__ float s_scores[Lsz];     // 16 KB; also reused to stage W
    __shared__ float s_tgt[Dsz];
    __shared__ float s_q[Dsz];
    __shared__ float s_wv[4];
    __shared__ int   s_wi[4];
    __shared__ float s_topv[Ksz];
    __shared__ int   s_topi[Ksz];

    const int b    = blockIdx.x;
    const int tid  = threadIdx.x;
    const int lane = tid & 63;
    const int wv   = tid >> 6;          // wave id 0..3

    // ---- Phase 1: q = (target / sqrt(D)) @ W^T ----------------------------
    // Stage W coalesced into s_scores (16 KB, free right now).
    for (int i = tid; i < Dsz * Dsz; i += 256) s_scores[i] = W[i];
    if (tid < Dsz) s_tgt[tid] = target[b * Dsz + tid] * 0.125f;  // 1/sqrt(64)
    __syncthreads();
    if (tid < Dsz) {
        float acc = 0.f;
        #pragma unroll
        for (int jj = 0; jj < Dsz; ++jj) {
            const int j = (tid + jj) & 63;          // rotate: 2-way LDS aliasing (free)
            acc += s_tgt[j] * s_scores[tid * Dsz + j];
        }
        s_q[tid] = acc;
    }
    __syncthreads();

    // Register-cache this lane's q fragment (constant across the whole stream).
    const int   c4 = (lane & 15) << 2;
    const float q0 = s_q[c4 + 0], q1 = s_q[c4 + 1], q2 = s_q[c4 + 2], q3 = s_q[c4 + 3];
    const int   sub = lane >> 4;        // which of the 4 rows this lane's group covers

    // ---- Phase 2: scores[l] = dot(seq[b,l,:], q) --------------------------
    // Per wave-iteration: 4 consecutive rows; lane i -> float4 #(r0*16 + i),
    // i.e. a contiguous 4 KB chunk, 16 B/lane fully coalesced.
    const float4* rowbase = (const float4*)(seq + (size_t)b * (Lsz * Dsz));
    #pragma unroll 4
    for (int r0 = wv * 4; r0 < Lsz; r0 += 16) {
        const float4 v = rowbase[r0 * 16 + lane];
        float p = v.x * q0 + v.y * q1 + v.z * q2 + v.w * q3;
        p += __shfl_xor(p, 1);
        p += __shfl_xor(p, 2);
        p += __shfl_xor(p, 4);
        p += __shfl_xor(p, 8);          // reduce within 16-lane group
        if ((lane & 15) == 0) s_scores[r0 + sub] = p;
    }
    __syncthreads();

    // ---- Phase 3: apply mask (coalesced) ----------------------------------
    const int isU8 = *flag;             // wave-uniform
    if (isU8) {
        const uint8_t* m8 = (const uint8_t*)maskp + (size_t)b * Lsz;
        for (int i = tid; i < Lsz; i += 256)
            if (!m8[i]) s_scores[i] = -1e9f;
    } else {
        const int* m32 = (const int*)maskp + (size_t)b * Lsz;
        for (int i = tid; i < Lsz; i += 256)
            if (!m32[i]) s_scores[i] = -1e9f;
    }
    __syncthreads();

    // ---- Phase 4: top-K=64 iterative argmax with cached local maxima ------
    // Thread t owns strided slots {t, t+256, ...}; scan ascending so equal
    // values keep the smallest index (matches lax.top_k tie order).
    float lv = s_scores[tid];
    int   li = tid;
    #pragma unroll
    for (int j = 1; j < 16; ++j) {
        const float v = s_scores[tid + j * 256];
        if (v > lv) { lv = v; li = tid + j * 256; }
    }

    for (int k = 0; k < Ksz; ++k) {
        // wave-level argmax (value desc, index asc on ties)
        float v = lv; int i = li;
        #pragma unroll
        for (int off = 1; off < 64; off <<= 1) {
            const float ov = __shfl_xor(v, off);
            const int   oi = __shfl_xor(i, off);
            if (ov > v || (ov == v && oi < i)) { v = ov; i = oi; }
        }
        if (lane == 0) { s_wv[wv] = v; s_wi[wv] = i; }
        __syncthreads();
        // all threads redundantly combine the 4 wave winners
        float gv = s_wv[0]; int gi = s_wi[0];
        #pragma unroll
        for (int w = 1; w < 4; ++w) {
            const float ov = s_wv[w]; const int oi = s_wi[w];
            if (ov > gv || (ov == gv && oi < gi)) { gv = ov; gi = oi; }
        }
        if (tid == 0) { s_topv[k] = gv; s_topi[k] = gi; }
        // only the owner of the extracted slot invalidates + rescans its 16
        if (li == gi) {
            s_scores[gi] = -INFINITY;
            lv = s_scores[tid]; li = tid;
            for (int j = 1; j < 16; ++j) {
                const float vv = s_scores[tid + j * 256];
                if (vv > lv) { lv = vv; li = tid + j * 256; }
            }
        }
        __syncthreads();
    }

    // ---- Phase 5: gather top rows + write mask ----------------------------
    float4* out4 = (float4*)out + (size_t)b * (Ksz * Dsz / 4);
    for (int i = tid; i < Ksz * Dsz / 4; i += 256) {   // 1024 float4s
        const int k  = i >> 4;        // 16 float4 per 64-float row
        const int d4 = i & 15;
        out4[i] = rowbase[s_topi[k] * 16 + d4];
    }
    float* outm = out + (size_t)Bsz * Ksz * Dsz;
    if (tid < Ksz) outm[b * Ksz + tid] = (s_topv[tid] > -1e8f) ? 1.0f : 0.0f;
}

extern "C" void kernel_launch(void* const* d_in, const int* in_sizes, int n_in,
                              void* d_out, int out_size, void* d_ws, size_t ws_size,
                              hipStream_t stream) {
    const float* target = (const float*)d_in[0];
    // d_in[1] = target_category (unused)
    const float* seq    = (const float*)d_in[2];
    // d_in[3] = seq_category (unused)
    const void*  mask   = d_in[4];
    // d_in[5] = top_k scalar (fixed at 64)
    const float* W      = (const float*)d_in[6];

    int* flag = (int*)d_ws;
    detect_mask_fmt<<<1, 256, 0, stream>>>((const uint8_t*)mask, flag);
    gsu_kernel<<<Bsz, 256, 0, stream>>>(target, seq, mask, W, flag, (float*)d_out);
}